// Round 9
// baseline (411.464 us; speedup 1.0000x reference)
//
#include <hip/hip_runtime.h>

#define N_NODES 100000
#define N_EDGES 1000000
#define D_FEAT  6
#define HIDDEN  300
#define HID_P   320          // padded hidden (multiple of 32)
#define MSG     100
#define OUTC    200          // 2*MSG
#define OUTC_P  208
#define MT      64           // edges per block
#define NT_H    (HID_P/16)   // 20 feature tiles for hidden layers
#define NT_M    13           // 13 feature tiles for messages (tile 12 partial)
#define KS_H    (HID_P/32)   // 10 k-steps of 32
#define NPART   (N_EDGES/MT) // 15625 per-block partials
#define LOG2E   1.44269504f
#define LN2     0.69314718f

typedef __bf16 bf16_t;
typedef __bf16 bf16x8 __attribute__((ext_vector_type(8)));
typedef __bf16 bf16x4 __attribute__((ext_vector_type(4)));
typedef __bf16 bf16x2 __attribute__((ext_vector_type(2)));
typedef float  floatx4 __attribute__((ext_vector_type(4)));

// ---------------- prep (weight pack) + base MAE loss, merged --------------------
// B-frag order pack: chunk of 512 el = one (ft,ks) fragment:
// el = ((ft*KS+ks)*64+lane)*8+j, element = W[k][n], n = ft*16+(lane&15),
// k = ks*32+(lane>>4)*8+j, zero-padded. W3 logvar cols (n>=MSG) pre-scaled by
// log2(e) so KL's exp is a bare v_exp_f32 (exp2).
#define PREP_BLOCKS 700
#define LOSS_BLOCKS 200
__global__ void prep_kernel(const float* __restrict__ W1, const float* __restrict__ W2,
                            const float* __restrict__ W3, bf16_t* __restrict__ W1P,
                            bf16_t* __restrict__ W2P, bf16_t* __restrict__ W3P,
                            const float* __restrict__ y, const float* __restrict__ t,
                            float* __restrict__ out) {
    if (blockIdx.x >= PREP_BLOCKS) {
        float s = 0.f;
        for (int i = (blockIdx.x - PREP_BLOCKS) * blockDim.x + threadIdx.x;
             i < N_NODES * 2; i += LOSS_BLOCKS * blockDim.x)
            s += fabsf(y[i] - t[i]);
        #pragma unroll
        for (int off = 32; off; off >>= 1) s += __shfl_down(s, off);
        __shared__ float red[4];
        if ((threadIdx.x & 63) == 0) red[threadIdx.x >> 6] = s;
        __syncthreads();
        if (threadIdx.x == 0)
            atomicAdd(out, (red[0] + red[1] + red[2] + red[3]) * (1.0f / N_NODES));
        return;
    }
    const int n1 = NT_H * 512;
    const int n2 = NT_H * KS_H * 512;
    const int n3 = NT_M * KS_H * 512;
    const int total = n1 + n2 + n3;
    for (int id = blockIdx.x * blockDim.x + threadIdx.x; id < total;
         id += PREP_BLOCKS * blockDim.x) {
        if (id < n1) {
            int nt = id >> 9, rem = id & 511, lane = rem >> 3, j = rem & 7;
            int n = nt * 16 + (lane & 15), k = (lane >> 4) * 8 + j;
            float v = (n < HIDDEN && k < 2 * D_FEAT) ? W1[k * HIDDEN + n] : 0.f;
            W1P[id] = (bf16_t)v;
        } else if (id < n1 + n2) {
            int r = id - n1;
            int chunk = r >> 9, rem = r & 511, lane = rem >> 3, j = rem & 7;
            int ks = chunk % KS_H, nt = chunk / KS_H;
            int n = nt * 16 + (lane & 15), k = ks * 32 + (lane >> 4) * 8 + j;
            float v = (n < HIDDEN && k < HIDDEN) ? W2[k * HIDDEN + n] : 0.f;
            W2P[r] = (bf16_t)v;
        } else {
            int r = id - n1 - n2;
            int chunk = r >> 9, rem = r & 511, lane = rem >> 3, j = rem & 7;
            int ks = chunk % KS_H, nt = chunk / KS_H;
            int n = nt * 16 + (lane & 15), k = ks * 32 + (lane >> 4) * 8 + j;
            float v = (n < OUTC && k < HIDDEN) ? W3[k * OUTC + n] : 0.f;
            if (n >= MSG) v *= LOG2E;            // logvar columns pre-scaled
            W3P[r] = (bf16_t)v;
        }
    }
}

// ---------------- final reduce: sum per-block KL partials into out -------------
#define RED_BLOCKS 64
__global__ void reduce_kernel(const float* __restrict__ part, float* __restrict__ out) {
    float s = 0.f;
    for (int i = blockIdx.x * blockDim.x + threadIdx.x; i < NPART;
         i += RED_BLOCKS * blockDim.x)
        s += part[i];
    #pragma unroll
    for (int off = 32; off; off >>= 1) s += __shfl_down(s, off);
    __shared__ float red[4];
    if ((threadIdx.x & 63) == 0) red[threadIdx.x >> 6] = s;
    __syncthreads();
    if (threadIdx.x == 0)
        atomicAdd(out, (red[0] + red[1] + red[2] + red[3]) * (0.5f / N_EDGES));
}

static __device__ __forceinline__ floatx4 mfma16(bf16x8 a, bf16x8 b, floatx4 c) {
    return __builtin_amdgcn_mfma_f32_16x16x32_bf16(a, b, c, 0, 0, 0);
}

// GEMM2 phase, explicitly software-pipelined 2 k-steps deep.
// R8 analysis: per CU per k-round, matrix pipe (1164 cyc) == L2 weight stream
// (1071 cyc) — co-critical with ~1-step compiler lookahead. Double-buffered
// wf/hb register sets give ~780-cycle load->use distance so the L2 stream
// rides under the MFMA clusters. All register indices compile-time.
template<int KSN, int SE>
__device__ __forceinline__ void gemm5x4(
    const bf16_t* __restrict__ Wbase0,     // W pack + (5w)*KSN*512
    const bf16_t* __restrict__ Hsrc, int lane,
    const floatx4 (&binit)[5], floatx4 (&acc)[5][4]) {
    #pragma unroll
    for (int i = 0; i < 5; i++)
        #pragma unroll
        for (int e = 0; e < 4; e++) acc[i][e] = binit[i];
    const bf16_t* Wb = Wbase0 + lane * 8;
    const bf16_t* Hb = Hsrc + lane * 8;
    bf16x8 wfA[5], wfB[5], hbA[4], hbB[4];
    #pragma unroll
    for (int i = 0; i < 5; i++) wfA[i] = *(const bf16x8*)(Wb + i * (KSN * 512));
    #pragma unroll
    for (int i = 0; i < 5; i++) wfB[i] = *(const bf16x8*)(Wb + i * (KSN * 512) + 512);
    #pragma unroll
    for (int e = 0; e < 4; e++) hbA[e] = *(const bf16x8*)(Hb + e * SE);
    #pragma unroll 1
    for (int ks = 0; ks < KSN - 2; ks += 2) {
        // load hb(ks+1) first: its 120cy LDS latency hides under A's MFMAs
        #pragma unroll
        for (int e = 0; e < 4; e++)
            hbB[e] = *(const bf16x8*)(Hb + (ks + 1) * 512 + e * SE);
        #pragma unroll
        for (int i = 0; i < 5; i++) {
            acc[i][0] = mfma16(wfA[i], hbA[0], acc[i][0]);
            acc[i][1] = mfma16(wfA[i], hbA[1], acc[i][1]);
            acc[i][2] = mfma16(wfA[i], hbA[2], acc[i][2]);
            acc[i][3] = mfma16(wfA[i], hbA[3], acc[i][3]);
        }
        #pragma unroll
        for (int i = 0; i < 5; i++)
            wfA[i] = *(const bf16x8*)(Wb + i * (KSN * 512) + (ks + 2) * 512);
        #pragma unroll
        for (int e = 0; e < 4; e++)
            hbA[e] = *(const bf16x8*)(Hb + (ks + 2) * 512 + e * SE);
        #pragma unroll
        for (int i = 0; i < 5; i++) {
            acc[i][0] = mfma16(wfB[i], hbB[0], acc[i][0]);
            acc[i][1] = mfma16(wfB[i], hbB[1], acc[i][1]);
            acc[i][2] = mfma16(wfB[i], hbB[2], acc[i][2]);
            acc[i][3] = mfma16(wfB[i], hbB[3], acc[i][3]);
        }
        #pragma unroll
        for (int i = 0; i < 5; i++)
            wfB[i] = *(const bf16x8*)(Wb + i * (KSN * 512) + (ks + 3) * 512);
    }
    // tail: ks = KSN-2 (A), KSN-1 (B)
    #pragma unroll
    for (int e = 0; e < 4; e++)
        hbB[e] = *(const bf16x8*)(Hb + (KSN - 1) * 512 + e * SE);
    #pragma unroll
    for (int i = 0; i < 5; i++) {
        acc[i][0] = mfma16(wfA[i], hbA[0], acc[i][0]);
        acc[i][1] = mfma16(wfA[i], hbA[1], acc[i][1]);
        acc[i][2] = mfma16(wfA[i], hbA[2], acc[i][2]);
        acc[i][3] = mfma16(wfA[i], hbA[3], acc[i][3]);
    }
    #pragma unroll
    for (int i = 0; i < 5; i++) {
        acc[i][0] = mfma16(wfB[i], hbB[0], acc[i][0]);
        acc[i][1] = mfma16(wfB[i], hbB[1], acc[i][1]);
        acc[i][2] = mfma16(wfB[i], hbB[2], acc[i][2]);
        acc[i][3] = mfma16(wfB[i], hbB[3], acc[i][3]);
    }
}

// Epilogue: relu + pack to bf16 (bias already in C), write in B-frag order.
// C/D layout: n(edge)=lane&15, m(feat)=(lane>>4)*4+reg  (verified, absmax 0).
__device__ __forceinline__ void epi5(
    bf16_t* __restrict__ Hf, int w, int q, int l16, const floatx4 (&acc)[5][4]) {
    #pragma unroll
    for (int i = 0; i < 5; i++) {
        int n0 = (5 * w + i) * 16 + 4 * q;
        int ks = n0 >> 5, lp = l16 + 16 * ((n0 >> 3) & 3), j0 = n0 & 7;
        #pragma unroll
        for (int e = 0; e < 4; e++) {
            bf16x4 pk;
            #pragma unroll
            for (int r = 0; r < 4; r++)
                pk[r] = (bf16_t)fmaxf(acc[i][e][r], 0.f);
            *(bf16x4*)&Hf[((e * KS_H + ks) * 64 + lp) * 8 + j0] = pk;
        }
    }
}

// ---------------- fused edge MLP + KL ------------------------------------------
// OPERAND SWAP: D = mfma(A=W_frag, B=H_frag) -> D rows = features, cols = edges.
// H in LDS in exact B-fragment order Hf[e][ks][lane][8]. Cooperative LDS-staged
// gather (R8-verified). NO same-address atomics (R5-R7: ~13ns serialization
// each at the coherence point): per-block partial -> store -> reduce kernel.
__global__ __launch_bounds__(256, 3) void mlp_kernel(
    const float* __restrict__ x, const int* __restrict__ ei,
    const bf16_t* __restrict__ W1P, const bf16_t* __restrict__ W2P,
    const bf16_t* __restrict__ W3P,
    const float* __restrict__ b1, const float* __restrict__ b2,
    const float* __restrict__ b3, float* __restrict__ part) {
    __shared__ __align__(16) bf16_t A1f[4 * 64 * 8];          // 4 KB, frag order
    __shared__ __align__(16) bf16_t Hf[4 * KS_H * 64 * 8];    // 40 KB, frag order
    __shared__ float red[4];

    const int tid  = threadIdx.x;
    const int w    = tid >> 6, lane = tid & 63;
    const int q    = lane >> 4, l16 = lane & 15;
    const long e0 = (long)blockIdx.x * MT;

    // ---- preload W1 fragments + b1/b2 C-init vectors (hide L2 behind gather) --
    bf16x8 wf1[5];
    floatx4 bv1[5], bv2[5];
    #pragma unroll
    for (int i = 0; i < 5; i++) {
        wf1[i] = *(const bf16x8*)&W1P[((5 * w + i) * 64 + lane) * 8];
        int n0 = (5 * w + i) * 16 + 4 * q;
        bv1[i] = (n0 < HIDDEN) ? *(const floatx4*)&b1[n0] : (floatx4){0.f, 0.f, 0.f, 0.f};
        bv2[i] = (n0 < HIDDEN) ? *(const floatx4*)&b2[n0] : (floatx4){0.f, 0.f, 0.f, 0.f};
    }

    // gather: edge features -> A1f fragment order, zero-padding embedded;
    // all writes disjoint, single barrier. elem(lane',j) = feat k of edge
    // (et*16 + (lane'&15)), k = (lane'>>4)*8 + j.
    if (tid < 2 * MT) {
        int m = tid >> 1, side = tid & 1;
        int node = ei[(long)side * N_EDGES + e0 + m];
        const float2* xr = (const float2*)(x + (long)node * D_FEAT);
        float2 v0 = xr[0], v1 = xr[1], v2 = xr[2];
        int et = m >> 4, ml = m & 15;
        bf16_t* Ab = &A1f[(et * 64 + ml) * 8];
        if (side == 0) {                       // k = 0..5 -> row ml, j 0..5
            bf16x4 lo = {(bf16_t)v0.x, (bf16_t)v0.y, (bf16_t)v1.x, (bf16_t)v1.y};
            *(bf16x4*)&Ab[0] = lo;
            bf16x2 mid = {(bf16_t)v2.x, (bf16_t)v2.y};
            *(bf16x2*)&Ab[4] = mid;
        } else {                               // k = 6,7 -> row ml; k = 8..11 -> row ml+16 (+zeros)
            bf16x2 hi2 = {(bf16_t)v0.x, (bf16_t)v0.y};
            *(bf16x2*)&Ab[6] = hi2;
            bf16x8 top = {(bf16_t)v1.x, (bf16_t)v1.y, (bf16_t)v2.x, (bf16_t)v2.y,
                          (bf16_t)0.f, (bf16_t)0.f, (bf16_t)0.f, (bf16_t)0.f};
            *(bf16x8*)&A1f[(et * 64 + ml + 16) * 8] = top;
        }
    } else {                                   // zero rows lane>=32 (k 16..31)
        int idx = tid - 128;                   // 0..127
        int et = idx >> 5, lr = 32 + (idx & 31);
        bf16x8 z = {};
        *(bf16x8*)&A1f[(et * 64 + lr) * 8] = z;
    }
    __syncthreads();

    floatx4 acc[5][4];

    // ---- GEMM1: h1 = relu(e @ W1 + b1), K=32 (one step), bias in C ----
    {
        bf16x8 hb0 = *(const bf16x8*)&A1f[lane * 8];
        bf16x8 hb1 = *(const bf16x8*)&A1f[(64 + lane) * 8];
        bf16x8 hb2 = *(const bf16x8*)&A1f[(128 + lane) * 8];
        bf16x8 hb3 = *(const bf16x8*)&A1f[(192 + lane) * 8];
        #pragma unroll
        for (int i = 0; i < 5; i++) {
            acc[i][0] = mfma16(wf1[i], hb0, bv1[i]);
            acc[i][1] = mfma16(wf1[i], hb1, bv1[i]);
            acc[i][2] = mfma16(wf1[i], hb2, bv1[i]);
            acc[i][3] = mfma16(wf1[i], hb3, bv1[i]);
        }
    }
    epi5(Hf, w, q, l16, acc);
    __syncthreads();

    // ---- GEMM2: h2 = relu(h1 @ W2 + b2), K=320, bias in C, pipelined ----
    gemm5x4<KS_H, KS_H * 512>(W2P + (5 * w) * (KS_H * 512), Hf, lane, bv2, acc);
    __syncthreads();   // all Hf(h1) reads done before overwrite
    epi5(Hf, w, q, l16, acc);
    __syncthreads();

    // ---- GEMM3: messages = h2 @ W3(+log2e-scaled lv) + b3 (bias in C), KL ----
    // Pipelined identically to GEMM2 (3 nt tiles + the shared tile-12 job).
    floatx4 a3[3][4], aq;
    const int n0q = 192 + 4 * q;                  // tile 12, logvar only
    {
        #pragma unroll
        for (int t = 0; t < 3; t++) {
            int n0 = (3 * w + t) * 16 + 4 * q;    // 0..191, always valid
            floatx4 bv = *(const floatx4*)&b3[n0];
            if (n0 >= MSG) bv = bv * LOG2E;       // logvar bias in log2e units
            #pragma unroll
            for (int e = 0; e < 4; e++) a3[t][e] = bv;
        }
        aq = (n0q < OUTC) ? *(const floatx4*)&b3[n0q] * LOG2E
                          : (floatx4){0.f, 0.f, 0.f, 0.f};
    }
    {
        const bf16_t* W3b = W3P + (3 * w) * (KS_H * 512) + lane * 8;
        const bf16_t* Wqb = W3P + 12 * (KS_H * 512) + lane * 8;
        const bf16_t* Hb  = Hf + lane * 8;
        const bf16_t* Hq  = Hf + w * (KS_H * 512) + lane * 8;   // et = w fragment
        bf16x8 wfA[3], wfB[3], hbA[4], hbB[4], wqA, wqB, hqA, hqB;
        #pragma unroll
        for (int t = 0; t < 3; t++) wfA[t] = *(const bf16x8*)(W3b + t * (KS_H * 512));
        #pragma unroll
        for (int t = 0; t < 3; t++) wfB[t] = *(const bf16x8*)(W3b + t * (KS_H * 512) + 512);
        wqA = *(const bf16x8*)(Wqb);
        wqB = *(const bf16x8*)(Wqb + 512);
        #pragma unroll
        for (int e = 0; e < 4; e++) hbA[e] = *(const bf16x8*)(Hb + e * (KS_H * 512));
        hqA = *(const bf16x8*)(Hq);
        #pragma unroll 1
        for (int ks = 0; ks < KS_H - 2; ks += 2) {
            #pragma unroll
            for (int e = 0; e < 4; e++)
                hbB[e] = *(const bf16x8*)(Hb + (ks + 1) * 512 + e * (KS_H * 512));
            hqB = *(const bf16x8*)(Hq + (ks + 1) * 512);
            #pragma unroll
            for (int t = 0; t < 3; t++) {
                a3[t][0] = mfma16(wfA[t], hbA[0], a3[t][0]);
                a3[t][1] = mfma16(wfA[t], hbA[1], a3[t][1]);
                a3[t][2] = mfma16(wfA[t], hbA[2], a3[t][2]);
                a3[t][3] = mfma16(wfA[t], hbA[3], a3[t][3]);
            }
            aq = mfma16(wqA, hqA, aq);
            #pragma unroll
            for (int t = 0; t < 3; t++)
                wfA[t] = *(const bf16x8*)(W3b + t * (KS_H * 512) + (ks + 2) * 512);
            wqA = *(const bf16x8*)(Wqb + (ks + 2) * 512);
            #pragma unroll
            for (int e = 0; e < 4; e++)
                hbA[e] = *(const bf16x8*)(Hb + (ks + 2) * 512 + e * (KS_H * 512));
            hqA = *(const bf16x8*)(Hq + (ks + 2) * 512);
            #pragma unroll
            for (int t = 0; t < 3; t++) {
                a3[t][0] = mfma16(wfB[t], hbB[0], a3[t][0]);
                a3[t][1] = mfma16(wfB[t], hbB[1], a3[t][1]);
                a3[t][2] = mfma16(wfB[t], hbB[2], a3[t][2]);
                a3[t][3] = mfma16(wfB[t], hbB[3], a3[t][3]);
            }
            aq = mfma16(wqB, hqB, aq);
            #pragma unroll
            for (int t = 0; t < 3; t++)
                wfB[t] = *(const bf16x8*)(W3b + t * (KS_H * 512) + (ks + 3) * 512);
            wqB = *(const bf16x8*)(Wqb + (ks + 3) * 512);
        }
        #pragma unroll
        for (int e = 0; e < 4; e++)
            hbB[e] = *(const bf16x8*)(Hb + (KS_H - 1) * 512 + e * (KS_H * 512));
        hqB = *(const bf16x8*)(Hq + (KS_H - 1) * 512);
        #pragma unroll
        for (int t = 0; t < 3; t++) {
            a3[t][0] = mfma16(wfA[t], hbA[0], a3[t][0]);
            a3[t][1] = mfma16(wfA[t], hbA[1], a3[t][1]);
            a3[t][2] = mfma16(wfA[t], hbA[2], a3[t][2]);
            a3[t][3] = mfma16(wfA[t], hbA[3], a3[t][3]);
        }
        aq = mfma16(wqA, hqA, aq);
        #pragma unroll
        for (int t = 0; t < 3; t++) {
            a3[t][0] = mfma16(wfB[t], hbB[0], a3[t][0]);
            a3[t][1] = mfma16(wfB[t], hbB[1], a3[t][1]);
            a3[t][2] = mfma16(wfB[t], hbB[2], a3[t][2]);
            a3[t][3] = mfma16(wfB[t], hbB[3], a3[t][3]);
        }
        aq = mfma16(wqB, hqB, aq);
    }
    // KL: mu -> sm += v*v; logvar (log2e units) -> se += exp2(v'), sv' += v',
    // cnt += group size. total = 0.5*(sm + se - ln2*sv' - cnt).
    float sm = 0.f, se = 0.f, svp = 0.f, cnt = 0.f;
    #pragma unroll
    for (int t = 0; t < 3; t++) {
        int n0 = (3 * w + t) * 16 + 4 * q;
        if (n0 < MSG) {                           // 4-runs never straddle 100
            #pragma unroll
            for (int e = 0; e < 4; e++)
                #pragma unroll
                for (int r = 0; r < 4; r++) {
                    float v = a3[t][e][r];
                    sm += v * v;
                }
        } else {
            #pragma unroll
            for (int e = 0; e < 4; e++)
                #pragma unroll
                for (int r = 0; r < 4; r++) {
                    float v = a3[t][e][r];
                    se += __builtin_exp2f(v);
                    svp += v;
                }
            cnt += 16.f;
        }
    }
    if (n0q < OUTC) {
        #pragma unroll
        for (int r = 0; r < 4; r++) {
            float v = aq[r];
            se += __builtin_exp2f(v);
            svp += v;
        }
        cnt += 4.f;
    }
    float s = sm + se - svp * LN2 - cnt;
    #pragma unroll
    for (int off = 32; off; off >>= 1) s += __shfl_down(s, off);
    if (lane == 0) red[w] = s;
    __syncthreads();
    if (tid == 0)
        part[blockIdx.x] = red[0] + red[1] + red[2] + red[3];   // plain store
}

extern "C" void kernel_launch(void* const* d_in, const int* in_sizes, int n_in,
                              void* d_out, int out_size, void* d_ws, size_t ws_size,
                              hipStream_t stream) {
    const float* x      = (const float*)d_in[0];
    const int*   ei     = (const int*)d_in[1];
    const float* y      = (const float*)d_in[2];
    const float* target = (const float*)d_in[3];
    const float* W1     = (const float*)d_in[4];
    const float* b1     = (const float*)d_in[5];
    const float* W2     = (const float*)d_in[6];
    const float* b2     = (const float*)d_in[7];
    const float* W3     = (const float*)d_in[8];
    const float* b3     = (const float*)d_in[9];
    float* out = (float*)d_out;

    bf16_t* W1P = (bf16_t*)d_ws;
    bf16_t* W2P = W1P + NT_H * 512;
    bf16_t* W3P = W2P + NT_H * KS_H * 512;
    float*  part = (float*)(W3P + NT_M * KS_H * 512);

    hipMemsetAsync(d_out, 0, sizeof(float), stream);
    prep_kernel<<<PREP_BLOCKS + LOSS_BLOCKS, 256, 0, stream>>>(
        W1, W2, W3, W1P, W2P, W3P, y, target, out);
    mlp_kernel<<<N_EDGES / MT, 256, 0, stream>>>(x, ei, W1P, W2P, W3P, b1, b2, b3, part);
    reduce_kernel<<<RED_BLOCKS, 256, 0, stream>>>(part, out);
}